// Round 5
// baseline (979.659 us; speedup 1.0000x reference)
//
#include <hip/hip_runtime.h>
#include <hip/hip_bf16.h>
#include <math.h>

typedef unsigned int   u32;
typedef unsigned short u16;
typedef float floatx4 __attribute__((ext_vector_type(4)));
typedef short bf16x8  __attribute__((ext_vector_type(8)));

#define MFMA16(a,b,c) __builtin_amdgcn_mfma_f32_16x16x32_bf16((a),(b),(c),0,0,0)

static __device__ __forceinline__ float bfbits2f(u16 h){
    return __uint_as_float(((u32)h) << 16);
}
static __device__ __forceinline__ u16 f2bfbits(float f){
    u32 u = __float_as_uint(f);
    u32 r = (u + 0x7fffu + ((u >> 16) & 1u)) >> 16;   // RNE
    return (u16)r;
}
static __device__ __forceinline__ bool sniff_bf16(const void* ln_g){
    return ((const u32*)ln_g)[0] == 0x3f803f80u;   // fp32 1.0 vs packed bf16 pair
}

// =======================================================================
// K0: pack weights -> bf16 ws, biases/ln params -> fp32 ws
// =======================================================================
struct PackJob { const void* src; void* dst; int n; int mode; };
struct PackParams { PackJob jobs[26]; const void* lng; };

__global__ __launch_bounds__(256) void k_pack(PackParams p){
    bool isb = sniff_bf16(p.lng);
    PackJob j = p.jobs[blockIdx.y];
    int i = blockIdx.x * 256 + threadIdx.x;
    if (i >= j.n) return;
    float v = isb ? bfbits2f(((const u16*)j.src)[i]) : ((const float*)j.src)[i];
    if (j.mode == 0) ((u16*)j.dst)[i]  = f2bfbits(v);
    else             ((float*)j.dst)[i] = v;
}

// =======================================================================
// K1: feature transpose [b][c][n] -> tokens [b][n][c] bf16
// =======================================================================
struct FtParams { const void* src[3]; u16* dst[3]; const void* lng; };

__global__ __launch_bounds__(256) void k_feat_t(FtParams p){
    bool isb = sniff_bf16(p.lng);
    int z = blockIdx.z; int si = z >> 1; int b = z & 1;
    const void* src = p.src[si]; u16* dst = p.dst[si];
    int n0 = blockIdx.x * 64, c0 = blockIdx.y * 64;
    __shared__ float tile[64][65];
    int t = threadIdx.x; int tx = t & 63; int ty = t >> 6;
    #pragma unroll
    for (int pp = 0; pp < 16; ++pp){
        int cl = ty + pp * 4;
        size_t off = ((size_t)b * 256 + c0 + cl) * 4096 + n0 + tx;
        float v = isb ? bfbits2f(((const u16*)src)[off]) : ((const float*)src)[off];
        tile[cl][tx] = v;
    }
    __syncthreads();
    #pragma unroll
    for (int pp = 0; pp < 16; ++pp){
        int nl = ty + pp * 4; int cl = tx;
        dst[((size_t)b * 4096 + n0 + nl) * 256 + c0 + cl] = f2bfbits(tile[cl][nl]);
    }
}

// =======================================================================
// K_gemm v3: 128(m) x 64(n) tile, 4 waves each 64x32 (4x2 16x16 subtiles)
// grid (64, 4, jobs) = 256 blocks/job -> full chip for every job.
// =======================================================================
struct GemmJob { const u16* A0; const u16* A1; const u16* A2;
                 const u16* W; const float* bias; const u16* res; u16* out; };
struct GemmParams { GemmJob jobs[5]; int K; int op; };

__global__ __launch_bounds__(256, 4) void k_gemm(GemmParams p){
    GemmJob j = p.jobs[blockIdx.z];
    int m0 = blockIdx.x * 128, n0 = blockIdx.y * 64;
    __shared__ __align__(16) u16 As[128][72];
    __shared__ __align__(16) u16 Bs[64][72];
    int t = threadIdx.x;
    int wave = t >> 6, lane = t & 63, l15 = lane & 15, quad = lane >> 4;
    int mw = (wave & 1) * 64, nw2 = (wave >> 1) * 32;

    int sr[4], sc[4], br[2], bc[2];
    #pragma unroll
    for (int i = 0; i < 4; ++i){ int g = i * 256 + t; sr[i] = g >> 3; sc[i] = g & 7; }
    #pragma unroll
    for (int i = 0; i < 2; ++i){ int g = i * 256 + t; br[i] = g >> 3; bc[i] = g & 7; }

    floatx4 acc[4][2];
    #pragma unroll
    for (int a = 0; a < 4; ++a)
        #pragma unroll
        for (int b = 0; b < 2; ++b) acc[a][b] = (floatx4){0.f,0.f,0.f,0.f};

    uint4 Ra[4], Rb[2];
    auto loadk = [&](int k0){
        const u16* Ap = (k0 < 256) ? j.A0 : (k0 < 512 ? j.A1 : j.A2);
        int koff = k0 & 255;
        #pragma unroll
        for (int i = 0; i < 4; ++i)
            Ra[i] = *(const uint4*)(Ap + (size_t)(m0 + sr[i]) * 256 + koff + sc[i] * 8);
        #pragma unroll
        for (int i = 0; i < 2; ++i)
            Rb[i] = *(const uint4*)(j.W + (size_t)(n0 + br[i]) * p.K + k0 + bc[i] * 8);
    };
    loadk(0);

    for (int k0 = 0; k0 < p.K; k0 += 64){
        __syncthreads();
        #pragma unroll
        for (int i = 0; i < 4; ++i) *(uint4*)&As[sr[i]][sc[i] * 8] = Ra[i];
        #pragma unroll
        for (int i = 0; i < 2; ++i) *(uint4*)&Bs[br[i]][bc[i] * 8] = Rb[i];
        __syncthreads();
        if (k0 + 64 < p.K) loadk(k0 + 64);
        #pragma unroll
        for (int kc = 0; kc < 2; ++kc){
            bf16x8 af[4], bfr[2];
            #pragma unroll
            for (int ms = 0; ms < 4; ++ms)
                af[ms] = *(const bf16x8*)&As[mw + ms * 16 + l15][kc * 32 + quad * 8];
            #pragma unroll
            for (int ns = 0; ns < 2; ++ns)
                bfr[ns] = *(const bf16x8*)&Bs[nw2 + ns * 16 + l15][kc * 32 + quad * 8];
            #pragma unroll
            for (int ms = 0; ms < 4; ++ms)
                #pragma unroll
                for (int ns = 0; ns < 2; ++ns)
                    acc[ms][ns] = MFMA16(af[ms], bfr[ns], acc[ms][ns]);
        }
    }
    #pragma unroll
    for (int ms = 0; ms < 4; ++ms)
        #pragma unroll
        for (int ns = 0; ns < 2; ++ns){
            int col = n0 + nw2 + ns * 16 + l15;
            float bias = j.bias[col];
            #pragma unroll
            for (int rg = 0; rg < 4; ++rg){
                int row = m0 + mw + ms * 16 + quad * 4 + rg;
                float v = acc[ms][ns][rg] + bias;
                if (p.op == 1)      v = 0.5f * v * (1.0f + erff(v * 0.70710678118f));
                else if (p.op == 2) v += bfbits2f(j.res[(size_t)row * 256 + col]);
                j.out[(size_t)row * 256 + col] = f2bfbits(v);
            }
        }
}

// =======================================================================
// K_ln: LayerNorm over c=256, wave-per-token (8192 tokens -> grid.x 2048!)
// =======================================================================
struct LnJob { const u16* src; u16* dst; };
struct LnParams { LnJob jobs[4]; const float* g; const float* b; };

__global__ __launch_bounds__(256, 4) void k_ln(LnParams p){
    LnJob j = p.jobs[blockIdx.y];
    int wave = threadIdx.x >> 6, lane = threadIdx.x & 63;
    size_t tok = (size_t)blockIdx.x * 4 + wave;
    const u16* row = j.src + tok * 256;
    ushort4 raw = *(const ushort4*)(row + lane * 4);
    float v0 = bfbits2f(raw.x), v1 = bfbits2f(raw.y), v2 = bfbits2f(raw.z), v3 = bfbits2f(raw.w);
    float s1 = v0 + v1 + v2 + v3;
    float s2 = v0*v0 + v1*v1 + v2*v2 + v3*v3;
    #pragma unroll
    for (int off = 1; off < 64; off <<= 1){
        s1 += __shfl_xor(s1, off);
        s2 += __shfl_xor(s2, off);
    }
    float mean = s1 * (1.f/256.f);
    float var  = s2 * (1.f/256.f) - mean * mean;
    float rstd = rsqrtf(var + 1e-5f);
    int c = lane * 4;
    ushort4 o;
    o.x = f2bfbits((v0 - mean) * rstd * p.g[c+0] + p.b[c+0]);
    o.y = f2bfbits((v1 - mean) * rstd * p.g[c+1] + p.b[c+1]);
    o.z = f2bfbits((v2 - mean) * rstd * p.g[c+2] + p.b[c+2]);
    o.w = f2bfbits((v3 - mean) * rstd * p.g[c+3] + p.b[c+3]);
    *(ushort4*)(j.dst + tok * 256 + c) = o;
}

// =======================================================================
// K_vt: bf16 transpose Vf [b][n][c] -> Vt [b][c][n]
// =======================================================================
__global__ __launch_bounds__(256, 4) void k_vt(const u16* __restrict__ Vf, u16* __restrict__ Vt){
    int b = blockIdx.z;
    int n0 = blockIdx.x * 64, c0 = blockIdx.y * 64;
    __shared__ u16 tile[64][66];
    int t = threadIdx.x; int tx = t & 63; int ty = t >> 6;
    #pragma unroll
    for (int pp = 0; pp < 16; ++pp){
        int nl = ty + pp * 4;
        tile[nl][tx] = Vf[((size_t)b * 4096 + n0 + nl) * 256 + c0 + tx];
    }
    __syncthreads();
    #pragma unroll
    for (int pp = 0; pp < 16; ++pp){
        int cl = ty + pp * 4; int nl = tx;
        Vt[((size_t)b * 256 + c0 + cl) * 4096 + n0 + nl] = tile[nl][cl];
    }
}

// =======================================================================
// K_flash v4: identical structure to v3 but __launch_bounds__(256, 2).
// (256,3) capped the unified VGPR file at ~170 (86 arch + 84 acc) ->
// compiler spilled loop-carried state to scratch: WRITE_SIZE blew up to
// 1.6 GB (128 B/thread/iter) and the kernel became store-bound at 42% HBM.
// (256,2) gives 128 arch + 128 acc: qf(32)+Rk/Rv(32)+state fits, o[16]=64
// AGPRs fits. Residency 2 blocks/CU (8 waves/CU) — R1 proved sufficient.
// LDS: K 16KB + V 16KB + P 4x16x36x2 = 37376 B.
// =======================================================================
struct FlashParams {
    const u16* Q[3]; const u16* K; const u16* Vt;
    u16* part[12]; float2* ml;
};

__global__ __launch_bounds__(256, 2) void k_flash(FlashParams p){
    int half = blockIdx.y & 1, sb = blockIdx.y >> 1;
    int s = sb >> 1, b = sb & 1;
    int m0 = blockIdx.x * 64;
    const u16* Q   = p.Q[s] + (size_t)b * 4096 * 256;
    const u16* Kf  = p.K    + (size_t)b * 4096 * 256;
    const u16* Vtg = p.Vt   + (size_t)b * 256 * 4096;
    u16* pb        = p.part[half * 6 + sb];
    float2* mlp    = p.ml + (size_t)(half * 6 + sb) * 4096;

    __shared__ __align__(16) u16 KL[32 * 256];   // slot(r,c)=r*32+(c^(r&7)), 16B granules
    __shared__ __align__(16) u16 VL[256 * 32];   // slot(d,c)=d*4+(c^((d>>2)&3))
    __shared__ __align__(16) u16 Pl[4][16][36];  // per-wave P, stride 36 (bank-clean)

    int t = threadIdx.x, wave = t >> 6, lane = t & 63, l15 = lane & 15, quad = lane >> 4;

    // Q fragments (A-layout): rows m0+wave*16+l15, k=quad*8+j
    bf16x8 qf[8];
    {
        const u16* qrow = Q + (size_t)(m0 + wave * 16 + l15) * 256 + quad * 8;
        #pragma unroll
        for (int kc = 0; kc < 8; ++kc) qf[kc] = *(const bf16x8*)(qrow + kc * 32);
    }
    floatx4 o[16];
    #pragma unroll
    for (int i = 0; i < 16; ++i) o[i] = (floatx4){0.f,0.f,0.f,0.f};
    float mrow[4] = {-INFINITY,-INFINITY,-INFINITY,-INFINITY};
    float lrow[4] = {0.f,0.f,0.f,0.f};

    // staging offsets: K 1024 granules, V 1024 granules, 4 each per thread
    int kb_off[4], kl_off[4], vs_off[4], vl_off[4];
    #pragma unroll
    for (int i = 0; i < 4; ++i){
        int g = i * 256 + t;
        int rk = g >> 5, ck = g & 31;
        kb_off[i] = rk * 256 + ck * 8;
        kl_off[i] = (rk * 32 + (ck ^ (rk & 7))) * 8;
        int dv = g >> 2, cv = g & 3;
        vs_off[i] = dv * 4096 + cv * 8;
        vl_off[i] = (dv * 4 + (cv ^ ((dv >> 2) & 3))) * 8;
    }

    uint4 Rk[4], Rv[4];
    auto loadc = [&](int kv0){
        #pragma unroll
        for (int i = 0; i < 4; ++i){
            Rk[i] = *(const uint4*)(Kf + (size_t)kv0 * 256 + kb_off[i]);
            Rv[i] = *(const uint4*)(Vtg + (size_t)kv0 + vs_off[i]);
        }
    };
    int kvbase = half * 2048;
    loadc(kvbase);

    int r7   = l15 & 7;          // K read swizzle key (row & 7)
    int vkey = (l15 >> 2) & 3;   // V read swizzle key

    for (int kv0 = kvbase; kv0 < kvbase + 2048; kv0 += 32){
        __syncthreads();
        #pragma unroll
        for (int i = 0; i < 4; ++i){
            *(uint4*)&KL[kl_off[i]] = Rk[i];
            *(uint4*)&VL[vl_off[i]] = Rv[i];
        }
        __syncthreads();
        if (kv0 + 32 < kvbase + 2048) loadc(kv0 + 32);

        // ---- S = Q K^T : 16q x 32kv per wave
        floatx4 sa[2];
        sa[0] = sa[1] = (floatx4){0.f,0.f,0.f,0.f};
        #pragma unroll
        for (int kvs = 0; kvs < 2; ++kvs){
            int rbase = (kvs * 16 + l15) * 32;
            #pragma unroll
            for (int kc = 0; kc < 8; ++kc){
                bf16x8 kbf = *(const bf16x8*)&KL[(rbase + ((kc * 4 + quad) ^ r7)) * 8];
                sa[kvs] = MFMA16(qf[kc], kbf, sa[kvs]);
            }
        }

        // ---- online softmax (wave-local; halves merged later)
        float al[4];
        int need = 0;
        #pragma unroll
        for (int rg = 0; rg < 4; ++rg){
            float m1 = fmaxf(sa[0][rg], sa[1][rg]);
            m1 = fmaxf(m1, __shfl_xor(m1, 1));
            m1 = fmaxf(m1, __shfl_xor(m1, 2));
            m1 = fmaxf(m1, __shfl_xor(m1, 4));
            m1 = fmaxf(m1, __shfl_xor(m1, 8));
            float mo = mrow[rg];
            float mn = fmaxf(mo, m1);
            need |= (mn > mo);
            al[rg] = __expf(mo - mn);
            mrow[rg] = mn;
        }
        float rs[4] = {0.f,0.f,0.f,0.f};
        #pragma unroll
        for (int kvs = 0; kvs < 2; ++kvs)
            #pragma unroll
            for (int rg = 0; rg < 4; ++rg){
                float pv = __expf(sa[kvs][rg] - mrow[rg]);
                rs[rg] += pv;
                Pl[wave][quad * 4 + rg][kvs * 16 + l15] = f2bfbits(pv);
            }
        #pragma unroll
        for (int rg = 0; rg < 4; ++rg){
            float r1 = rs[rg];
            r1 += __shfl_xor(r1, 1); r1 += __shfl_xor(r1, 2);
            r1 += __shfl_xor(r1, 4); r1 += __shfl_xor(r1, 8);
            lrow[rg] = lrow[rg] * al[rg] + r1;
        }
        if (__ballot(need) != 0ull){
            #pragma unroll
            for (int dc = 0; dc < 16; ++dc)
                #pragma unroll
                for (int rg = 0; rg < 4; ++rg) o[dc][rg] *= al[rg];
        }

        // ---- P fragment (per-wave buffer, no barrier needed)
        bf16x8 pa = *(const bf16x8*)&Pl[wave][l15][quad * 8];

        // ---- O += P V
        #pragma unroll
        for (int dc = 0; dc < 16; ++dc){
            int dv = dc * 16 + l15;
            bf16x8 vb = *(const bf16x8*)&VL[(dv * 4 + (quad ^ vkey)) * 8];
            o[dc] = MFMA16(pa, vb, o[dc]);
        }
    }

    // ---- epilogue: write UNNORMALIZED partial O (bf16) + m,l
    #pragma unroll
    for (int dc = 0; dc < 16; ++dc){
        int c = dc * 16 + l15;
        #pragma unroll
        for (int rg = 0; rg < 4; ++rg){
            int row = m0 + wave * 16 + quad * 4 + rg;
            pb[(size_t)row * 256 + c] = f2bfbits(o[dc][rg]);
        }
    }
    if (l15 == 0){
        #pragma unroll
        for (int rg = 0; rg < 4; ++rg){
            int row = m0 + wave * 16 + quad * 4 + rg;
            mlp[row] = make_float2(mrow[rg], lrow[rg]);
        }
    }
}

// =======================================================================
// K_merge: combine 2 kv-halves, /l, +residual, LN -> Y bf16
// wave per token, grid (1024, 6): 4096 tokens per (s,b)
// =======================================================================
struct MergeParams {
    const u16* part[12]; const float2* ml;
    const u16* Res[3]; u16* Out[3];
    const float* g; const float* b;
};

__global__ __launch_bounds__(256, 4) void k_merge(MergeParams p){
    int sb = blockIdx.y; int s = sb >> 1; int bb = sb & 1;
    int wave = threadIdx.x >> 6, lane = threadIdx.x & 63;
    int tok = blockIdx.x * 4 + wave;
    const u16* p0 = p.part[sb];
    const u16* p1 = p.part[6 + sb];
    float2 ml0 = p.ml[(size_t)sb * 4096 + tok];
    float2 ml1 = p.ml[(size_t)(6 + sb) * 4096 + tok];
    float M  = fmaxf(ml0.x, ml1.x);
    float w0 = __expf(ml0.x - M), w1 = __expf(ml1.x - M);
    float rden = 1.0f / (w0 * ml0.y + w1 * ml1.y);
    int d = lane * 4;
    ushort4 a0 = *(const ushort4*)(p0 + (size_t)tok * 256 + d);
    ushort4 a1 = *(const ushort4*)(p1 + (size_t)tok * 256 + d);
    const u16* res = p.Res[s] + ((size_t)bb * 4096 + tok) * 256 + d;
    ushort4 rr = *(const ushort4*)res;
    float v0 = (w0 * bfbits2f(a0.x) + w1 * bfbits2f(a1.x)) * rden + bfbits2f(rr.x);
    float v1 = (w0 * bfbits2f(a0.y) + w1 * bfbits2f(a1.y)) * rden + bfbits2f(rr.y);
    float v2 = (w0 * bfbits2f(a0.z) + w1 * bfbits2f(a1.z)) * rden + bfbits2f(rr.z);
    float v3 = (w0 * bfbits2f(a0.w) + w1 * bfbits2f(a1.w)) * rden + bfbits2f(rr.w);
    float s1 = v0 + v1 + v2 + v3;
    float s2 = v0*v0 + v1*v1 + v2*v2 + v3*v3;
    #pragma unroll
    for (int off = 1; off < 64; off <<= 1){
        s1 += __shfl_xor(s1, off);
        s2 += __shfl_xor(s2, off);
    }
    float mean = s1 * (1.f/256.f);
    float var  = s2 * (1.f/256.f) - mean * mean;
    float rstd = rsqrtf(var + 1e-5f);
    ushort4 ov;
    ov.x = f2bfbits((v0 - mean) * rstd * p.g[d+0] + p.b[d+0]);
    ov.y = f2bfbits((v1 - mean) * rstd * p.g[d+1] + p.b[d+1]);
    ov.z = f2bfbits((v2 - mean) * rstd * p.g[d+2] + p.b[d+2]);
    ov.w = f2bfbits((v3 - mean) * rstd * p.g[d+3] + p.b[d+3]);
    *(ushort4*)(p.Out[s] + ((size_t)bb * 4096 + tok) * 256 + d) = ov;
}

// =======================================================================
// K_out: F_s [b][n][c] bf16 -> d_out [s][b][c][n] (fp32 or bf16 per flag)
// =======================================================================
struct OutTParams { const u16* F[3]; void* out; const void* lng; };

__global__ __launch_bounds__(256, 4) void k_out_t(OutTParams p){
    bool isb = sniff_bf16(p.lng);
    int z = blockIdx.z; int s = z >> 1; int b = z & 1;
    const u16* F = p.F[s];
    int n0 = blockIdx.x * 64, c0 = blockIdx.y * 64;
    __shared__ u16 tile[64][66];
    int t = threadIdx.x; int tx = t & 63; int ty = t >> 6;
    #pragma unroll
    for (int pp = 0; pp < 16; ++pp){
        int nl = ty + pp * 4;
        tile[nl][tx] = F[((size_t)b * 4096 + n0 + nl) * 256 + c0 + tx];
    }
    __syncthreads();
    size_t obase = ((size_t)s * 2 + b) * 256 * 4096;
    #pragma unroll
    for (int pp = 0; pp < 16; ++pp){
        int cl = ty + pp * 4; int nl = tx;
        u16 raw = tile[nl][cl];
        size_t off = obase + (size_t)(c0 + cl) * 4096 + n0 + nl;
        if (isb) ((u16*)p.out)[off]   = raw;
        else     ((float*)p.out)[off] = bfbits2f(raw);
    }
}

// =======================================================================
// host side
// =======================================================================
extern "C" void kernel_launch(void* const* d_in, const int* in_sizes, int n_in,
                              void* d_out, int out_size, void* d_ws, size_t ws_size,
                              hipStream_t stream) {
    (void)in_sizes; (void)n_in; (void)out_size; (void)ws_size;
    const size_t SLOT = (size_t)2 * 4096 * 256;   // elems (4 MB)
    u16* ws = (u16*)d_ws;
    auto slot = [&](int i){ return ws + (size_t)i * SLOT; };

    u16 *Tc = slot(0),  *Tw = slot(1),  *Tcl = slot(2),  *Tm = slot(3);
    u16 *Lc = slot(4),  *Lw = slot(5),  *Lcl = slot(6),  *Lm = slot(7);
    u16 *Q1 = slot(8),  *Q2 = slot(9),  *Q3  = slot(10);
    u16 *Kf = slot(11), *Vf = slot(12), *Vt  = slot(13);
    u16 *Yc = slot(14), *Yw = slot(15), *Ycl = slot(16);
    u16 *Hc = Q1, *Hw = Q2, *Hcl = Q3;     // Q dead after flash
    u16 *Zc = Lc, *Zw = Lw, *Zcl = Lcl;    // L dead after K4; partials dead after merge
    u16 *Fc = Kf, *Fw = Vf, *Fcl = Vt;     // K/V dead after flash

    u16* wbase = slot(17);
    u16 *mixw = wbase;
    u16 *q1w = wbase + 196608, *q2w = q1w + 65536, *q3w = q2w + 65536;
    u16 *kw  = q3w + 65536,    *vw  = kw  + 65536;
    u16 *cw1 = vw  + 65536, *cw2 = cw1 + 65536, *ww1 = cw2 + 65536,
        *ww2 = ww1 + 65536, *clw1 = ww2 + 65536, *clw2 = clw1 + 65536;
    float* pbase = (float*)(wbase + 1048576);
    float *mixb = pbase,        *lng = pbase+256,  *lnb = pbase+512,
          *q1b = pbase+768,  *q2b = pbase+1024, *q3b = pbase+1280,
          *kb  = pbase+1536, *vb  = pbase+1792,
          *cb1 = pbase+2048, *cb2 = pbase+2304, *wb1 = pbase+2560,
          *wb2 = pbase+2816, *clb1= pbase+3072, *clb2= pbase+3328;
    float2* mlp = (float2*)(pbase + 4096);   // 12x4096 float2 = 393 KB, fits slot 17

    // partial-O buffers (12 x 2MB) overlaid on slots dead by flash time
    const int pslots[6] = {3, 4, 5, 6, 7, 12};
    u16* part[12];
    for (int i = 0; i < 12; ++i)
        part[i] = slot(pslots[i >> 1]) + (size_t)(i & 1) * (SLOT / 2);

    // ---- K0 pack ----
    {
        PackParams pp;
        const int widx[12] = {3,7,9,11,13,15,17,19,21,23,25,27};
        u16* wdst[12] = {mixw,q1w,q2w,q3w,kw,vw,cw1,cw2,ww1,ww2,clw1,clw2};
        for (int i = 0; i < 12; ++i)
            pp.jobs[i] = PackJob{ d_in[widx[i]], wdst[i], (i==0?196608:65536), 0 };
        const int pidx[14] = {4,5,6,8,10,12,14,16,18,20,22,24,26,28};
        float* pdst[14] = {mixb,lng,lnb,q1b,q2b,q3b,kb,vb,cb1,cb2,wb1,wb2,clb1,clb2};
        for (int i = 0; i < 14; ++i)
            pp.jobs[12+i] = PackJob{ d_in[pidx[i]], pdst[i], 256, 1 };
        pp.lng = d_in[5];
        hipLaunchKernelGGL(k_pack, dim3(768, 26), dim3(256), 0, stream, pp);
    }
    // ---- K1 tokenize features ----
    {
        FtParams fp;
        fp.src[0] = d_in[0]; fp.src[1] = d_in[1]; fp.src[2] = d_in[2];
        fp.dst[0] = Tc; fp.dst[1] = Tw; fp.dst[2] = Tcl;
        fp.lng = d_in[5];
        hipLaunchKernelGGL(k_feat_t, dim3(64, 4, 6), dim3(256), 0, stream, fp);
    }
    // ---- K2 mix GEMM (K=768) ----
    {
        GemmParams gp; gp.K = 768; gp.op = 0;
        gp.jobs[0] = GemmJob{ Tc, Tw, Tcl, mixw, mixb, nullptr, Tm };
        hipLaunchKernelGGL(k_gemm, dim3(64, 4, 1), dim3(256), 0, stream, gp);
    }
    // ---- K3 LN of the 4 token sets (8192 tokens -> grid.x 2048) ----
    {
        LnParams lp; lp.g = lng; lp.b = lnb;
        lp.jobs[0] = LnJob{Tc, Lc}; lp.jobs[1] = LnJob{Tw, Lw};
        lp.jobs[2] = LnJob{Tcl, Lcl}; lp.jobs[3] = LnJob{Tm, Lm};
        hipLaunchKernelGGL(k_ln, dim3(2048, 4), dim3(256), 0, stream, lp);
    }
    // ---- K4 q1,q2,q3,k,v GEMMs ----
    {
        GemmParams gp; gp.K = 256; gp.op = 0;
        gp.jobs[0] = GemmJob{ Lc,  nullptr, nullptr, q1w, q1b, nullptr, Q1 };
        gp.jobs[1] = GemmJob{ Lw,  nullptr, nullptr, q2w, q2b, nullptr, Q2 };
        gp.jobs[2] = GemmJob{ Lcl, nullptr, nullptr, q3w, q3b, nullptr, Q3 };
        gp.jobs[3] = GemmJob{ Lm,  nullptr, nullptr, kw,  kb,  nullptr, Kf };
        gp.jobs[4] = GemmJob{ Lm,  nullptr, nullptr, vw,  vb,  nullptr, Vf };
        hipLaunchKernelGGL(k_gemm, dim3(64, 4, 5), dim3(256), 0, stream, gp);
    }
    // ---- K4b V transpose ----
    hipLaunchKernelGGL(k_vt, dim3(64, 4, 2), dim3(256), 0, stream, Vf, Vt);
    // ---- K5 flash attention (kv-split 2, partials) ----
    {
        FlashParams fp;
        fp.Q[0] = Q1; fp.Q[1] = Q2; fp.Q[2] = Q3;
        fp.K = Kf; fp.Vt = Vt;
        for (int i = 0; i < 12; ++i) fp.part[i] = part[i];
        fp.ml = mlp;
        hipLaunchKernelGGL(k_flash, dim3(64, 12), dim3(256), 0, stream, fp);
    }
    // ---- K5b merge halves + residual + LN ----
    {
        MergeParams mp;
        for (int i = 0; i < 12; ++i) mp.part[i] = part[i];
        mp.ml = mlp;
        mp.Res[0] = Tc; mp.Res[1] = Tw; mp.Res[2] = Tcl;
        mp.Out[0] = Yc; mp.Out[1] = Yw; mp.Out[2] = Ycl;
        mp.g = lng; mp.b = lnb;
        hipLaunchKernelGGL(k_merge, dim3(1024, 6), dim3(256), 0, stream, mp);
    }
    // ---- K6a MLP fc1 + GELU ----
    {
        GemmParams gp; gp.K = 256; gp.op = 1;
        gp.jobs[0] = GemmJob{ Yc,  nullptr, nullptr, cw1,  cb1,  nullptr, Hc };
        gp.jobs[1] = GemmJob{ Yw,  nullptr, nullptr, ww1,  wb1,  nullptr, Hw };
        gp.jobs[2] = GemmJob{ Ycl, nullptr, nullptr, clw1, clb1, nullptr, Hcl };
        hipLaunchKernelGGL(k_gemm, dim3(64, 4, 3), dim3(256), 0, stream, gp);
    }
    // ---- K6b MLP fc2 + residual ----
    {
        GemmParams gp; gp.K = 256; gp.op = 2;
        gp.jobs[0] = GemmJob{ Hc,  nullptr, nullptr, cw2,  cb2,  Yc,  Zc };
        gp.jobs[1] = GemmJob{ Hw,  nullptr, nullptr, ww2,  wb2,  Yw,  Zw };
        gp.jobs[2] = GemmJob{ Hcl, nullptr, nullptr, clw2, clb2, Ycl, Zcl };
        hipLaunchKernelGGL(k_gemm, dim3(64, 4, 3), dim3(256), 0, stream, gp);
    }
    // ---- K7a final LN (8192 tokens -> grid.x 2048) ----
    {
        LnParams lp; lp.g = lng; lp.b = lnb;
        lp.jobs[0] = LnJob{Zc, Fc}; lp.jobs[1] = LnJob{Zw, Fw};
        lp.jobs[2] = LnJob{Zcl, Fcl}; lp.jobs[3] = LnJob{Zc, Fc};
        hipLaunchKernelGGL(k_ln, dim3(2048, 3), dim3(256), 0, stream, lp);
    }
    // ---- K7b untokenize + dtype-correct store ----
    {
        OutTParams op;
        op.F[0] = Fc; op.F[1] = Fw; op.F[2] = Fcl;
        op.out = d_out; op.lng = d_in[5];
        hipLaunchKernelGGL(k_out_t, dim3(64, 4, 6), dim3(256), 0, stream, op);
    }
}

// Round 6
// 521.490 us; speedup vs baseline: 1.8786x; 1.8786x over previous
//
#include <hip/hip_runtime.h>
#include <hip/hip_bf16.h>
#include <math.h>

typedef unsigned int   u32;
typedef unsigned short u16;
typedef float floatx4 __attribute__((ext_vector_type(4)));
typedef short bf16x8  __attribute__((ext_vector_type(8)));

#define MFMA16(a,b,c) __builtin_amdgcn_mfma_f32_16x16x32_bf16((a),(b),(c),0,0,0)

// async global->LDS DMA: 16B per lane, dst = wave-uniform base + lane*16
#define GLDS(gp, lp) __builtin_amdgcn_global_load_lds( \
    (const __attribute__((address_space(1))) void*)(gp), \
    (__attribute__((address_space(3))) void*)(lp), 16, 0, 0)

static __device__ __forceinline__ float bfbits2f(u16 h){
    return __uint_as_float(((u32)h) << 16);
}
static __device__ __forceinline__ u16 f2bfbits(float f){
    u32 u = __float_as_uint(f);
    u32 r = (u + 0x7fffu + ((u >> 16) & 1u)) >> 16;   // RNE
    return (u16)r;
}
static __device__ __forceinline__ bool sniff_bf16(const void* ln_g){
    return ((const u32*)ln_g)[0] == 0x3f803f80u;   // fp32 1.0 vs packed bf16 pair
}

// =======================================================================
// K0: pack weights -> bf16 ws, biases/ln params -> fp32 ws
// =======================================================================
struct PackJob { const void* src; void* dst; int n; int mode; int off; };
struct PackParams { PackJob jobs[28]; const void* lng; };

__global__ __launch_bounds__(256) void k_pack(PackParams p){
    bool isb = sniff_bf16(p.lng);
    PackJob j = p.jobs[blockIdx.y];
    int i = blockIdx.x * 256 + threadIdx.x;
    if (i >= j.n) return;
    int si = j.off + i;
    float v = isb ? bfbits2f(((const u16*)j.src)[si]) : ((const float*)j.src)[si];
    if (j.mode == 0) ((u16*)j.dst)[i]  = f2bfbits(v);
    else             ((float*)j.dst)[i] = v;
}

// =======================================================================
// K1: feature transpose [b][c][n] -> tokens [b][n][c] bf16
// =======================================================================
struct FtParams { const void* src[3]; u16* dst[3]; const void* lng; };

__global__ __launch_bounds__(256) void k_feat_t(FtParams p){
    bool isb = sniff_bf16(p.lng);
    int z = blockIdx.z; int si = z >> 1; int b = z & 1;
    const void* src = p.src[si]; u16* dst = p.dst[si];
    int n0 = blockIdx.x * 64, c0 = blockIdx.y * 64;
    __shared__ float tile[64][65];
    int t = threadIdx.x; int tx = t & 63; int ty = t >> 6;
    #pragma unroll
    for (int pp = 0; pp < 16; ++pp){
        int cl = ty + pp * 4;
        size_t off = ((size_t)b * 256 + c0 + cl) * 4096 + n0 + tx;
        float v = isb ? bfbits2f(((const u16*)src)[off]) : ((const float*)src)[off];
        tile[cl][tx] = v;
    }
    __syncthreads();
    #pragma unroll
    for (int pp = 0; pp < 16; ++pp){
        int nl = ty + pp * 4; int cl = tx;
        dst[((size_t)b * 4096 + n0 + nl) * 256 + c0 + cl] = f2bfbits(tile[cl][nl]);
    }
}

// =======================================================================
// K_gemm: 128(m) x 64(n) tile, 4 waves each 64x32 (4x2 16x16 subtiles)
// =======================================================================
struct GemmJob { const u16* A0; const u16* A1; const u16* A2;
                 const u16* W; const float* bias; const u16* res; u16* out; };
struct GemmParams { GemmJob jobs[5]; int K; int op; };

__global__ __launch_bounds__(256, 4) void k_gemm(GemmParams p){
    GemmJob j = p.jobs[blockIdx.z];
    int m0 = blockIdx.x * 128, n0 = blockIdx.y * 64;
    __shared__ __align__(16) u16 As[128][72];
    __shared__ __align__(16) u16 Bs[64][72];
    int t = threadIdx.x;
    int wave = t >> 6, lane = t & 63, l15 = lane & 15, quad = lane >> 4;
    int mw = (wave & 1) * 64, nw2 = (wave >> 1) * 32;

    int sr[4], sc[4], br[2], bc[2];
    #pragma unroll
    for (int i = 0; i < 4; ++i){ int g = i * 256 + t; sr[i] = g >> 3; sc[i] = g & 7; }
    #pragma unroll
    for (int i = 0; i < 2; ++i){ int g = i * 256 + t; br[i] = g >> 3; bc[i] = g & 7; }

    floatx4 acc[4][2];
    #pragma unroll
    for (int a = 0; a < 4; ++a)
        #pragma unroll
        for (int b = 0; b < 2; ++b) acc[a][b] = (floatx4){0.f,0.f,0.f,0.f};

    uint4 Ra[4], Rb[2];
    auto loadk = [&](int k0){
        const u16* Ap = (k0 < 256) ? j.A0 : (k0 < 512 ? j.A1 : j.A2);
        int koff = k0 & 255;
        #pragma unroll
        for (int i = 0; i < 4; ++i)
            Ra[i] = *(const uint4*)(Ap + (size_t)(m0 + sr[i]) * 256 + koff + sc[i] * 8);
        #pragma unroll
        for (int i = 0; i < 2; ++i)
            Rb[i] = *(const uint4*)(j.W + (size_t)(n0 + br[i]) * p.K + k0 + bc[i] * 8);
    };
    loadk(0);

    for (int k0 = 0; k0 < p.K; k0 += 64){
        __syncthreads();
        #pragma unroll
        for (int i = 0; i < 4; ++i) *(uint4*)&As[sr[i]][sc[i] * 8] = Ra[i];
        #pragma unroll
        for (int i = 0; i < 2; ++i) *(uint4*)&Bs[br[i]][bc[i] * 8] = Rb[i];
        __syncthreads();
        if (k0 + 64 < p.K) loadk(k0 + 64);
        #pragma unroll
        for (int kc = 0; kc < 2; ++kc){
            bf16x8 af[4], bfr[2];
            #pragma unroll
            for (int ms = 0; ms < 4; ++ms)
                af[ms] = *(const bf16x8*)&As[mw + ms * 16 + l15][kc * 32 + quad * 8];
            #pragma unroll
            for (int ns = 0; ns < 2; ++ns)
                bfr[ns] = *(const bf16x8*)&Bs[nw2 + ns * 16 + l15][kc * 32 + quad * 8];
            #pragma unroll
            for (int ms = 0; ms < 4; ++ms)
                #pragma unroll
                for (int ns = 0; ns < 2; ++ns)
                    acc[ms][ns] = MFMA16(af[ms], bfr[ns], acc[ms][ns]);
        }
    }
    #pragma unroll
    for (int ms = 0; ms < 4; ++ms)
        #pragma unroll
        for (int ns = 0; ns < 2; ++ns){
            int col = n0 + nw2 + ns * 16 + l15;
            float bias = j.bias[col];
            #pragma unroll
            for (int rg = 0; rg < 4; ++rg){
                int row = m0 + mw + ms * 16 + quad * 4 + rg;
                float v = acc[ms][ns][rg] + bias;
                if (p.op == 1)      v = 0.5f * v * (1.0f + erff(v * 0.70710678118f));
                else if (p.op == 2) v += bfbits2f(j.res[(size_t)row * 256 + col]);
                j.out[(size_t)row * 256 + col] = f2bfbits(v);
            }
        }
}

// =======================================================================
// K_ln: LayerNorm over c=256, wave-per-token (8192 tokens -> grid.x 2048)
// =======================================================================
struct LnJob { const u16* src; u16* dst; };
struct LnParams { LnJob jobs[4]; const float* g; const float* b; };

__global__ __launch_bounds__(256, 4) void k_ln(LnParams p){
    LnJob j = p.jobs[blockIdx.y];
    int wave = threadIdx.x >> 6, lane = threadIdx.x & 63;
    size_t tok = (size_t)blockIdx.x * 4 + wave;
    const u16* row = j.src + tok * 256;
    ushort4 raw = *(const ushort4*)(row + lane * 4);
    float v0 = bfbits2f(raw.x), v1 = bfbits2f(raw.y), v2 = bfbits2f(raw.z), v3 = bfbits2f(raw.w);
    float s1 = v0 + v1 + v2 + v3;
    float s2 = v0*v0 + v1*v1 + v2*v2 + v3*v3;
    #pragma unroll
    for (int off = 1; off < 64; off <<= 1){
        s1 += __shfl_xor(s1, off);
        s2 += __shfl_xor(s2, off);
    }
    float mean = s1 * (1.f/256.f);
    float var  = s2 * (1.f/256.f) - mean * mean;
    float rstd = rsqrtf(var + 1e-5f);
    int c = lane * 4;
    ushort4 o;
    o.x = f2bfbits((v0 - mean) * rstd * p.g[c+0] + p.b[c+0]);
    o.y = f2bfbits((v1 - mean) * rstd * p.g[c+1] + p.b[c+1]);
    o.z = f2bfbits((v2 - mean) * rstd * p.g[c+2] + p.b[c+2]);
    o.w = f2bfbits((v3 - mean) * rstd * p.g[c+3] + p.b[c+3]);
    *(ushort4*)(j.dst + tok * 256 + c) = o;
}

// =======================================================================
// K_vt: bf16 transpose Vf [b][n][c] -> Vt [b][c][n]
// =======================================================================
__global__ __launch_bounds__(256, 4) void k_vt(const u16* __restrict__ Vf, u16* __restrict__ Vt){
    int b = blockIdx.z;
    int n0 = blockIdx.x * 64, c0 = blockIdx.y * 64;
    __shared__ u16 tile[64][66];
    int t = threadIdx.x; int tx = t & 63; int ty = t >> 6;
    #pragma unroll
    for (int pp = 0; pp < 16; ++pp){
        int nl = ty + pp * 4;
        tile[nl][tx] = Vf[((size_t)b * 4096 + n0 + nl) * 256 + c0 + tx];
    }
    __syncthreads();
    #pragma unroll
    for (int pp = 0; pp < 16; ++pp){
        int cl = ty + pp * 4; int nl = tx;
        Vt[((size_t)b * 256 + c0 + cl) * 4096 + n0 + nl] = tile[nl][cl];
    }
}

// =======================================================================
// K_flash v5: async-DMA staging (global_load_lds 16B), zero prefetch regs.
// K double-buffered (2x16KB), V single (16KB), P per-wave (4KB) = 53248 B.
// __launch_bounds__(256,3): 3 blocks/CU, grid 768 = one balanced round.
// Raw s_barrier + s_waitcnt vmcnt(N) (0xF74 = vmcnt<=4, lgkm/exp ignored)
// so the K(i+1)/V(i+1) DMAs stay in flight across barriers.
// Swizzle moved to the DMA *source* address (XOR within 128B segments,
// coalescing preserved); read-side swizzles identical to R4 (verified).
// =======================================================================
struct FlashParams {
    const u16* Q[3]; const u16* K; const u16* Vt;
    u16* part[12]; float2* ml;
};

__global__ __launch_bounds__(256, 3) void k_flash(FlashParams p){
    int half = blockIdx.y & 1, sb = blockIdx.y >> 1;
    int s = sb >> 1, b = sb & 1;
    int m0 = blockIdx.x * 64;
    const u16* Q   = p.Q[s] + (size_t)b * 4096 * 256;
    const u16* Kf  = p.K    + (size_t)b * 4096 * 256;
    const u16* Vtg = p.Vt   + (size_t)b * 256 * 4096;
    u16* pb        = p.part[half * 6 + sb];
    float2* mlp    = p.ml + (size_t)(half * 6 + sb) * 4096;

    __shared__ __align__(16) u16 KL[2][32 * 256];  // slot(r,c)=r*32+(c^(r&7)) granules
    __shared__ __align__(16) u16 VL[256 * 32];     // slot(d,c)=d*4+(c^((d>>2)&3))
    __shared__ __align__(16) u16 Pl[4][16][32];    // per-wave P

    int t = threadIdx.x, wave = t >> 6, lane = t & 63, l15 = lane & 15, quad = lane >> 4;

    // DMA source element-offsets; LDS slot for lane is implicit (base+lane*16)
    int kfull[4], voff[4];
    #pragma unroll
    for (int j = 0; j < 4; ++j){
        int g = wave * 256 + j * 64 + lane;
        int r = g >> 5, cs = g & 31;
        kfull[j] = r * 256 + (cs ^ (r & 7)) * 8;        // K[row r][swizzled granule]
        int d = g >> 2, cv = g & 3;
        voff[j]  = d * 4096 + (cv ^ ((d >> 2) & 3)) * 8; // V^T[row d][swizzled granule]
    }
    int gbase = wave * 2048;   // this wave's staging region (elements)

    bf16x8 qf[8];
    {
        const u16* qrow = Q + (size_t)(m0 + wave * 16 + l15) * 256 + quad * 8;
        #pragma unroll
        for (int kc = 0; kc < 8; ++kc) qf[kc] = *(const bf16x8*)(qrow + kc * 32);
    }
    floatx4 o[16];
    #pragma unroll
    for (int i = 0; i < 16; ++i) o[i] = (floatx4){0.f,0.f,0.f,0.f};
    float mrow[4] = {-INFINITY,-INFINITY,-INFINITY,-INFINITY};
    float lrow[4] = {0.f,0.f,0.f,0.f};

    int kvbase = half * 2048;

    // prologue: stage chunk 0
    #pragma unroll
    for (int j = 0; j < 4; ++j)
        GLDS(Kf + (size_t)kvbase * 256 + kfull[j], &KL[0][gbase + j * 512]);
    #pragma unroll
    for (int j = 0; j < 4; ++j)
        GLDS(Vtg + (size_t)kvbase + voff[j], &VL[gbase + j * 512]);

    int r7 = l15 & 7, vkey = (l15 >> 2) & 3;

    for (int i = 0; i < 64; ++i){
        __builtin_amdgcn_s_waitcnt(0xF74);   // own K(i) DMAs done (4 newest = V(i))
        __builtin_amdgcn_s_barrier();        // all waves' K(i) landed
        const u16* KLc = KL[i & 1];
        int kvn = kvbase + i * 32 + 32;
        if (i < 63){
            u16* kdst = &KL[(i + 1) & 1][gbase];
            #pragma unroll
            for (int j = 0; j < 4; ++j)
                GLDS(Kf + (size_t)kvn * 256 + kfull[j], kdst + j * 512);
        }
        // ---- S = Q K^T : 16q x 32kv per wave
        floatx4 sa[2];
        sa[0] = sa[1] = (floatx4){0.f,0.f,0.f,0.f};
        #pragma unroll
        for (int kvs = 0; kvs < 2; ++kvs){
            int rbase = (kvs * 16 + l15) * 32;
            #pragma unroll
            for (int kc = 0; kc < 8; ++kc){
                bf16x8 kbf = *(const bf16x8*)&KLc[(rbase + ((kc * 4 + quad) ^ r7)) * 8];
                sa[kvs] = MFMA16(qf[kc], kbf, sa[kvs]);
            }
        }
        if (i < 63) __builtin_amdgcn_s_waitcnt(0xF74);  // V(i) done (K(i+1) newer)
        else        __builtin_amdgcn_s_waitcnt(0xF70);  // last iter: drain V
        __builtin_amdgcn_s_barrier();                   // all waves' V(i) landed

        // ---- online softmax (wave-local; halves merged later)
        float al[4];
        int need = 0;
        #pragma unroll
        for (int rg = 0; rg < 4; ++rg){
            float m1 = fmaxf(sa[0][rg], sa[1][rg]);
            m1 = fmaxf(m1, __shfl_xor(m1, 1));
            m1 = fmaxf(m1, __shfl_xor(m1, 2));
            m1 = fmaxf(m1, __shfl_xor(m1, 4));
            m1 = fmaxf(m1, __shfl_xor(m1, 8));
            float mo = mrow[rg];
            float mn = fmaxf(mo, m1);
            need |= (mn > mo);
            al[rg] = __expf(mo - mn);
            mrow[rg] = mn;
        }
        float rs[4] = {0.f,0.f,0.f,0.f};
        #pragma unroll
        for (int kvs = 0; kvs < 2; ++kvs)
            #pragma unroll
            for (int rg = 0; rg < 4; ++rg){
                float pv = __expf(sa[kvs][rg] - mrow[rg]);
                rs[rg] += pv;
                Pl[wave][quad * 4 + rg][kvs * 16 + l15] = f2bfbits(pv);
            }
        #pragma unroll
        for (int rg = 0; rg < 4; ++rg){
            float r1 = rs[rg];
            r1 += __shfl_xor(r1, 1); r1 += __shfl_xor(r1, 2);
            r1 += __shfl_xor(r1, 4); r1 += __shfl_xor(r1, 8);
            lrow[rg] = lrow[rg] * al[rg] + r1;
        }
        if (__ballot(need) != 0ull){
            #pragma unroll
            for (int dc = 0; dc < 16; ++dc)
                #pragma unroll
                for (int rg = 0; rg < 4; ++rg) o[dc][rg] *= al[rg];
        }

        // ---- P fragment (per-wave buffer, wave-local ordering)
        bf16x8 pa = *(const bf16x8*)&Pl[wave][l15][quad * 8];

        // ---- O += P V
        #pragma unroll
        for (int dc = 0; dc < 16; ++dc){
            int dv = dc * 16 + l15;
            bf16x8 vb = *(const bf16x8*)&VL[(dv * 4 + (quad ^ vkey)) * 8];
            o[dc] = MFMA16(pa, vb, o[dc]);
        }
        __builtin_amdgcn_s_barrier();        // all waves done reading VL / KLc
        if (i < 63){
            #pragma unroll
            for (int j = 0; j < 4; ++j)
                GLDS(Vtg + (size_t)kvn + voff[j], &VL[gbase + j * 512]);
        }
    }

    // ---- epilogue: write UNNORMALIZED partial O (bf16) + m,l
    #pragma unroll
    for (int dc = 0; dc < 16; ++dc){
        int c = dc * 16 + l15;
        #pragma unroll
        for (int rg = 0; rg < 4; ++rg){
            int row = m0 + wave * 16 + quad * 4 + rg;
            pb[(size_t)row * 256 + c] = f2bfbits(o[dc][rg]);
        }
    }
    if (l15 == 0){
        #pragma unroll
        for (int rg = 0; rg < 4; ++rg){
            int row = m0 + wave * 16 + quad * 4 + rg;
            mlp[row] = make_float2(mrow[rg], lrow[rg]);
        }
    }
}

// =======================================================================
// K_merge: combine 2 kv-halves, /l, +residual, LN -> Y bf16
// wave per token, grid (1024, 6): 4096 tokens per (s,b)
// =======================================================================
struct MergeParams {
    const u16* part[12]; const float2* ml;
    const u16* Res[3]; u16* Out[3];
    const float* g; const float* b;
};

__global__ __launch_bounds__(256, 4) void k_merge(MergeParams p){
    int sb = blockIdx.y; int s = sb >> 1; int bb = sb & 1;
    int wave = threadIdx.x >> 6, lane = threadIdx.x & 63;
    int tok = blockIdx.x * 4 + wave;
    const u16* p0 = p.part[sb];
    const u16* p1 = p.part[6 + sb];
    float2 ml0 = p.ml[(size_t)sb * 4096 + tok];
    float2 ml1 = p.ml[(size_t)(6 + sb) * 4096 + tok];
    float M  = fmaxf(ml0.x, ml1.x);
    float w0 = __expf(ml0.x - M), w1 = __expf(ml1.x - M);
    float rden = 1.0f / (w0 * ml0.y + w1 * ml1.y);
    int d = lane * 4;
    ushort4 a0 = *(const ushort4*)(p0 + (size_t)tok * 256 + d);
    ushort4 a1 = *(const ushort4*)(p1 + (size_t)tok * 256 + d);
    const u16* res = p.Res[s] + ((size_t)bb * 4096 + tok) * 256 + d;
    ushort4 rr = *(const ushort4*)res;
    float v0 = (w0 * bfbits2f(a0.x) + w1 * bfbits2f(a1.x)) * rden + bfbits2f(rr.x);
    float v1 = (w0 * bfbits2f(a0.y) + w1 * bfbits2f(a1.y)) * rden + bfbits2f(rr.y);
    float v2 = (w0 * bfbits2f(a0.z) + w1 * bfbits2f(a1.z)) * rden + bfbits2f(rr.z);
    float v3 = (w0 * bfbits2f(a0.w) + w1 * bfbits2f(a1.w)) * rden + bfbits2f(rr.w);
    float s1 = v0 + v1 + v2 + v3;
    float s2 = v0*v0 + v1*v1 + v2*v2 + v3*v3;
    #pragma unroll
    for (int off = 1; off < 64; off <<= 1){
        s1 += __shfl_xor(s1, off);
        s2 += __shfl_xor(s2, off);
    }
    float mean = s1 * (1.f/256.f);
    float var  = s2 * (1.f/256.f) - mean * mean;
    float rstd = rsqrtf(var + 1e-5f);
    ushort4 ov;
    ov.x = f2bfbits((v0 - mean) * rstd * p.g[d+0] + p.b[d+0]);
    ov.y = f2bfbits((v1 - mean) * rstd * p.g[d+1] + p.b[d+1]);
    ov.z = f2bfbits((v2 - mean) * rstd * p.g[d+2] + p.b[d+2]);
    ov.w = f2bfbits((v3 - mean) * rstd * p.g[d+3] + p.b[d+3]);
    *(ushort4*)(p.Out[s] + ((size_t)bb * 4096 + tok) * 256 + d) = ov;
}

// =======================================================================
// K_out: F_s [b][n][c] bf16 -> d_out [s][b][c][n] (fp32 or bf16 per flag)
// =======================================================================
struct OutTParams { const u16* F[3]; void* out; const void* lng; };

__global__ __launch_bounds__(256, 4) void k_out_t(OutTParams p){
    bool isb = sniff_bf16(p.lng);
    int z = blockIdx.z; int s = z >> 1; int b = z & 1;
    const u16* F = p.F[s];
    int n0 = blockIdx.x * 64, c0 = blockIdx.y * 64;
    __shared__ u16 tile[64][66];
    int t = threadIdx.x; int tx = t & 63; int ty = t >> 6;
    #pragma unroll
    for (int pp = 0; pp < 16; ++pp){
        int nl = ty + pp * 4;
        tile[nl][tx] = F[((size_t)b * 4096 + n0 + nl) * 256 + c0 + tx];
    }
    __syncthreads();
    size_t obase = ((size_t)s * 2 + b) * 256 * 4096;
    #pragma unroll
    for (int pp = 0; pp < 16; ++pp){
        int cl = ty + pp * 4; int nl = tx;
        u16 raw = tile[nl][cl];
        size_t off = obase + (size_t)(c0 + cl) * 4096 + n0 + nl;
        if (isb) ((u16*)p.out)[off]   = raw;
        else     ((float*)p.out)[off] = bfbits2f(raw);
    }
}

// =======================================================================
// host side
// =======================================================================
extern "C" void kernel_launch(void* const* d_in, const int* in_sizes, int n_in,
                              void* d_out, int out_size, void* d_ws, size_t ws_size,
                              hipStream_t stream) {
    (void)in_sizes; (void)n_in; (void)out_size; (void)ws_size;
    const size_t SLOT = (size_t)2 * 4096 * 256;   // elems (4 MB)
    u16* ws = (u16*)d_ws;
    auto slot = [&](int i){ return ws + (size_t)i * SLOT; };

    u16 *Tc = slot(0),  *Tw = slot(1),  *Tcl = slot(2),  *Tm = slot(3);
    u16 *Lc = slot(4),  *Lw = slot(5),  *Lcl = slot(6),  *Lm = slot(7);
    u16 *Q1 = slot(8),  *Q2 = slot(9),  *Q3  = slot(10);
    u16 *Kf = slot(11), *Vf = slot(12), *Vt  = slot(13);
    u16 *Yc = slot(14), *Yw = slot(15), *Ycl = slot(16);
    u16 *Hc = Q1, *Hw = Q2, *Hcl = Q3;     // Q dead after flash
    u16 *Zc = Lc, *Zw = Lw, *Zcl = Lcl;    // L dead after K4; partials dead after merge
    u16 *Fc = Kf, *Fw = Vf, *Fcl = Vt;     // K/V dead after flash

    u16* wbase = slot(17);
    u16 *mixw = wbase;
    u16 *q1w = wbase + 196608, *q2w = q1w + 65536, *q3w = q2w + 65536;
    u16 *kw  = q3w + 65536,    *vw  = kw  + 65536;
    u16 *cw1 = vw  + 65536, *cw2 = cw1 + 65536, *ww1 = cw2 + 65536,
        *ww2 = ww1 + 65536, *clw1 = ww2 + 65536, *clw2 = clw1 + 65536;
    float* pbase = (float*)(wbase + 1048576);
    float *mixb = pbase,        *lng = pbase+256,  *lnb = pbase+512,
          *q1b = pbase+768,  *q2b = pbase+1024, *q3b = pbase+1280,
          *kb  = pbase+1536, *vb  = pbase+1792,
          *cb1 = pbase+2048, *cb2 = pbase+2304, *wb1 = pbase+2560,
          *wb2 = pbase+2816, *clb1= pbase+3072, *clb2= pbase+3328;
    float2* mlp = (float2*)(pbase + 4096);   // 12x4096 float2 = 393 KB, fits slot 17

    // partial-O buffers (12 x 2MB) overlaid on slots dead by flash time
    const int pslots[6] = {3, 4, 5, 6, 7, 12};
    u16* part[12];
    for (int i = 0; i < 12; ++i)
        part[i] = slot(pslots[i >> 1]) + (size_t)(i & 1) * (SLOT / 2);

    // ---- K0 pack (mix weight split into 3 jobs of 65536) ----
    {
        PackParams pp;
        int nj = 0;
        for (int c = 0; c < 3; ++c)
            pp.jobs[nj++] = PackJob{ d_in[3], mixw + 65536 * c, 65536, 0, 65536 * c };
        const int widx[11] = {7,9,11,13,15,17,19,21,23,25,27};
        u16* wdst[11] = {q1w,q2w,q3w,kw,vw,cw1,cw2,ww1,ww2,clw1,clw2};
        for (int i = 0; i < 11; ++i)
            pp.jobs[nj++] = PackJob{ d_in[widx[i]], wdst[i], 65536, 0, 0 };
        const int pidx[14] = {4,5,6,8,10,12,14,16,18,20,22,24,26,28};
        float* pdst[14] = {mixb,lng,lnb,q1b,q2b,q3b,kb,vb,cb1,cb2,wb1,wb2,clb1,clb2};
        for (int i = 0; i < 14; ++i)
            pp.jobs[nj++] = PackJob{ d_in[pidx[i]], pdst[i], 256, 1, 0 };
        pp.lng = d_in[5];
        hipLaunchKernelGGL(k_pack, dim3(256, 28), dim3(256), 0, stream, pp);
    }
    // ---- K1 tokenize features ----
    {
        FtParams fp;
        fp.src[0] = d_in[0]; fp.src[1] = d_in[1]; fp.src[2] = d_in[2];
        fp.dst[0] = Tc; fp.dst[1] = Tw; fp.dst[2] = Tcl;
        fp.lng = d_in[5];
        hipLaunchKernelGGL(k_feat_t, dim3(64, 4, 6), dim3(256), 0, stream, fp);
    }
    // ---- K2 mix GEMM (K=768) ----
    {
        GemmParams gp; gp.K = 768; gp.op = 0;
        gp.jobs[0] = GemmJob{ Tc, Tw, Tcl, mixw, mixb, nullptr, Tm };
        hipLaunchKernelGGL(k_gemm, dim3(64, 4, 1), dim3(256), 0, stream, gp);
    }
    // ---- K3 LN of the 4 token sets (8192 tokens -> grid.x 2048) ----
    {
        LnParams lp; lp.g = lng; lp.b = lnb;
        lp.jobs[0] = LnJob{Tc, Lc}; lp.jobs[1] = LnJob{Tw, Lw};
        lp.jobs[2] = LnJob{Tcl, Lcl}; lp.jobs[3] = LnJob{Tm, Lm};
        hipLaunchKernelGGL(k_ln, dim3(2048, 4), dim3(256), 0, stream, lp);
    }
    // ---- K4 q1,q2,q3,k,v GEMMs ----
    {
        GemmParams gp; gp.K = 256; gp.op = 0;
        gp.jobs[0] = GemmJob{ Lc,  nullptr, nullptr, q1w, q1b, nullptr, Q1 };
        gp.jobs[1] = GemmJob{ Lw,  nullptr, nullptr, q2w, q2b, nullptr, Q2 };
        gp.jobs[2] = GemmJob{ Lcl, nullptr, nullptr, q3w, q3b, nullptr, Q3 };
        gp.jobs[3] = GemmJob{ Lm,  nullptr, nullptr, kw,  kb,  nullptr, Kf };
        gp.jobs[4] = GemmJob{ Lm,  nullptr, nullptr, vw,  vb,  nullptr, Vf };
        hipLaunchKernelGGL(k_gemm, dim3(64, 4, 5), dim3(256), 0, stream, gp);
    }
    // ---- K4b V transpose ----
    hipLaunchKernelGGL(k_vt, dim3(64, 4, 2), dim3(256), 0, stream, Vf, Vt);
    // ---- K5 flash attention (kv-split 2, async DMA staging) ----
    {
        FlashParams fp;
        fp.Q[0] = Q1; fp.Q[1] = Q2; fp.Q[2] = Q3;
        fp.K = Kf; fp.Vt = Vt;
        for (int i = 0; i < 12; ++i) fp.part[i] = part[i];
        fp.ml = mlp;
        hipLaunchKernelGGL(k_flash, dim3(64, 12), dim3(256), 0, stream, fp);
    }
    // ---- K5b merge halves + residual + LN ----
    {
        MergeParams mp;
        for (int i = 0; i < 12; ++i) mp.part[i] = part[i];
        mp.ml = mlp;
        mp.Res[0] = Tc; mp.Res[1] = Tw; mp.Res[2] = Tcl;
        mp.Out[0] = Yc; mp.Out[1] = Yw; mp.Out[2] = Ycl;
        mp.g = lng; mp.b = lnb;
        hipLaunchKernelGGL(k_merge, dim3(1024, 6), dim3(256), 0, stream, mp);
    }
    // ---- K6a MLP fc1 + GELU ----
    {
        GemmParams gp; gp.K = 256; gp.op = 1;
        gp.jobs[0] = GemmJob{ Yc,  nullptr, nullptr, cw1,  cb1,  nullptr, Hc };
        gp.jobs[1] = GemmJob{ Yw,  nullptr, nullptr, ww1,  wb1,  nullptr, Hw };
        gp.jobs[2] = GemmJob{ Ycl, nullptr, nullptr, clw1, clb1, nullptr, Hcl };
        hipLaunchKernelGGL(k_gemm, dim3(64, 4, 3), dim3(256), 0, stream, gp);
    }
    // ---- K6b MLP fc2 + residual ----
    {
        GemmParams gp; gp.K = 256; gp.op = 2;
        gp.jobs[0] = GemmJob{ Hc,  nullptr, nullptr, cw2,  cb2,  Yc,  Zc };
        gp.jobs[1] = GemmJob{ Hw,  nullptr, nullptr, ww2,  wb2,  Yw,  Zw };
        gp.jobs[2] = GemmJob{ Hcl, nullptr, nullptr, clw2, clb2, Ycl, Zcl };
        hipLaunchKernelGGL(k_gemm, dim3(64, 4, 3), dim3(256), 0, stream, gp);
    }
    // ---- K7a final LN (8192 tokens -> grid.x 2048) ----
    {
        LnParams lp; lp.g = lng; lp.b = lnb;
        lp.jobs[0] = LnJob{Zc, Fc}; lp.jobs[1] = LnJob{Zw, Fw};
        lp.jobs[2] = LnJob{Zcl, Fcl}; lp.jobs[3] = LnJob{Zc, Fc};
        hipLaunchKernelGGL(k_ln, dim3(2048, 3), dim3(256), 0, stream, lp);
    }
    // ---- K7b untokenize + dtype-correct store ----
    {
        OutTParams op;
        op.F[0] = Fc; op.F[1] = Fw; op.F[2] = Fcl;
        op.out = d_out; op.lng = d_in[5];
        hipLaunchKernelGGL(k_out_t, dim3(64, 4, 6), dim3(256), 0, stream, op);
    }
}